// Round 1
// baseline (911.867 us; speedup 1.0000x reference)
//
#include <hip/hip_runtime.h>
#include <cstdint>
#include <cstddef>

#define BATCH 32768
#define NHID 256
#define KTOT 2048            // NHID * 8
#define BM 64                // batch rows per block
#define BK 32                // K per MFMA chunk
#define NCHUNK (KTOT / BK)   // 64
#define MAT_ELEMS (NHID * KTOT)   // 524288 elements per weight matrix
#define CHUNK_SHORTS (16 * 64 * 8) // 8192 shorts = 16KB per K-chunk of packed W

typedef __attribute__((ext_vector_type(8))) short short8;
typedef __attribute__((ext_vector_type(4))) float f32x4;

__device__ __forceinline__ float fast_tanh(float x) {
    // t = 1 - 2/(e^{2x}+1); monotone, |t|<1, no NaN/Inf for any finite x
    float e = __expf(2.0f * x);
    return 1.0f - 2.0f / (e + 1.0f);
}

__device__ __forceinline__ unsigned short f2bf(float f) {
    union { float f; unsigned u; } v; v.f = f;
    unsigned r = v.u + 0x7fffu + ((v.u >> 16) & 1u);  // RNE
    return (unsigned short)(r >> 16);
}

// ---------------------------------------------------------------- RFF embed
__global__ __launch_bounds__(256) void kan_rff(
    const float* __restrict__ x, const float* __restrict__ B, float* __restrict__ h)
{
    int t = blockIdx.x * 256 + threadIdx.x;   // over BATCH*128
    int j = t & 127;
    int b = t >> 7;
    float x0 = x[b * 3 + 0], x1 = x[b * 3 + 1], x2 = x[b * 3 + 2];
    float z = x0 * B[j] + x1 * B[128 + j] + x2 * B[256 + j];
    float sn, cs;
    __sincosf(z, &sn, &cs);
    h[(size_t)b * NHID + j] = cs;
    h[(size_t)b * NHID + 128 + j] = sn;
}

// ------------------------------------------------- weight prepack to bf16 frag order
// packed[((kc*16 + nt)*64 + lane)*8 + j] = bf16( W[nt*16 + (lane&15)][kc*32 + (lane>>4)*8 + j] )
__global__ __launch_bounds__(256) void kan_prepack(
    const float* __restrict__ CU, const float* __restrict__ CV,
    const float* __restrict__ Cin, const float* __restrict__ Cout,
    unsigned short* __restrict__ pw)
{
    int mat = blockIdx.y;   // 0=CU 1=CV 2..5=Cin[i] 6..9=Cout[i]
    const float* src;
    if (mat == 0) src = CU;
    else if (mat == 1) src = CV;
    else if (mat < 6) src = Cin + (size_t)(mat - 2) * MAT_ELEMS;
    else src = Cout + (size_t)(mat - 6) * MAT_ELEMS;
    unsigned short* dst = pw + (size_t)mat * MAT_ELEMS;

    int p8 = blockIdx.x * 256 + threadIdx.x;   // 0..65535 (16B groups)
    int l  = p8 & 63;
    int nt = (p8 >> 6) & 15;
    int kc = p8 >> 10;
    int o = nt * 16 + (l & 15);
    int k = kc * 32 + ((l >> 4) << 3);
    const float* s = src + (size_t)o * KTOT + k;
    short8 v;
#pragma unroll
    for (int j = 0; j < 8; ++j) v[j] = (short)f2bf(s[j]);
    *(short8*)(dst + (size_t)p8 * 8) = v;
}

// ---------------------------------------------------------------- fused KAN GEMM
// Y[b,o] = sum_k T_d(tanh(act[b,i])) * W[o,k],  k = i*8+d
// mode 0: out = g                      (u/v heads; blockIdx.y selects pw/out)
// mode 1: out = s*(v + g*(u-v)) + (1-s)*idb    (s = *scal; residual blend)
__global__ __launch_bounds__(256) void kan_gemm(
    const float* __restrict__ act,
    const unsigned short* __restrict__ pw0,
    const unsigned short* __restrict__ pw1,
    float* out0, float* out1,
    const float* __restrict__ ubuf, const float* __restrict__ vbuf,
    const float* idb, const float* __restrict__ scal,
    int mode)
{
    __shared__ unsigned short basis[BM * 40];        // 64 rows, stride 40 shorts (80B, pad vs conflicts)
    __shared__ unsigned short bwt[2][CHUNK_SHORTS];  // double-buffered B chunk (2 x 16KB)

    const int tid = threadIdx.x;
    const int wv = tid >> 6;
    const int lane = tid & 63;
    const int b0 = blockIdx.x * BM;

    const unsigned short* pw = (blockIdx.y == 0) ? pw0 : pw1;
    float* out = (blockIdx.y == 0) ? out0 : out1;

    f32x4 acc[4][4];
#pragma unroll
    for (int i = 0; i < 4; ++i)
#pragma unroll
        for (int j = 0; j < 4; ++j)
            acc[i][j] = (f32x4){0.f, 0.f, 0.f, 0.f};

    // basis-producer role: row br (0..63), input-within-chunk bil (0..3)
    const int br = tid >> 2;
    const int bil = tid & 3;
    const float* hrow = act + (size_t)(b0 + br) * NHID;

    // preamble: async-stage B chunk 0
    {
        const unsigned short* g = pw;
#pragma unroll
        for (int q = 0; q < 4; ++q) {
            int c = wv * 4 + q;
            __builtin_amdgcn_global_load_lds(
                (const __attribute__((address_space(1))) unsigned int*)(g + c * 512 + lane * 8),
                (__attribute__((address_space(3))) unsigned int*)(&bwt[0][c * 512]),
                16, 0, 0);
        }
    }

    float hval = hrow[bil];   // h for chunk 0

    for (int kc = 0; kc < NCHUNK; ++kc) {
        // --- Chebyshev basis for this chunk: thread -> 8 bf16 (one (row, input) pair)
        {
            float t = fast_tanh(hval);
            float t2 = t + t;
            short8 sv;
            sv[0] = (short)0x3f80;          // T0 = 1.0 in bf16
            sv[1] = (short)f2bf(t);         // T1 = t
            float Tm = 1.0f, Tc = t;
#pragma unroll
            for (int d = 2; d < 8; ++d) {
                float Tn = fmaf(t2, Tc, -Tm);   // T_d = 2t*T_{d-1} - T_{d-2}
                sv[d] = (short)f2bf(Tn);
                Tm = Tc; Tc = Tn;
            }
            *(short8*)&basis[br * 40 + bil * 8] = sv;
        }
        __syncthreads();   // basis visible; B[kc] resident (drained at prev barrier)

        // --- prefetch next B chunk + next h while MFMAs run
        if (kc + 1 < NCHUNK) {
            const unsigned short* g = pw + (size_t)(kc + 1) * CHUNK_SHORTS;
            unsigned short* dstb = bwt[(kc + 1) & 1];
#pragma unroll
            for (int q = 0; q < 4; ++q) {
                int c = wv * 4 + q;
                __builtin_amdgcn_global_load_lds(
                    (const __attribute__((address_space(1))) unsigned int*)(g + c * 512 + lane * 8),
                    (__attribute__((address_space(3))) unsigned int*)(dstb + c * 512),
                    16, 0, 0);
            }
            hval = hrow[(kc + 1) * 4 + bil];
        }

        // --- fragments + 16 MFMAs (wave covers m 0..63, n = wv*64..wv*64+63)
        const unsigned short* bb = bwt[kc & 1];
        short8 af[4], bfr[4];
#pragma unroll
        for (int mf = 0; mf < 4; ++mf)
            af[mf] = *(const short8*)&basis[(mf * 16 + (lane & 15)) * 40 + (lane >> 4) * 8];
#pragma unroll
        for (int nf = 0; nf < 4; ++nf)
            bfr[nf] = *(const short8*)&bb[((wv * 4 + nf) * 64 + lane) * 8];
#pragma unroll
        for (int mf = 0; mf < 4; ++mf)
#pragma unroll
            for (int nf = 0; nf < 4; ++nf)
                acc[mf][nf] = __builtin_amdgcn_mfma_f32_16x16x32_bf16(
                    af[mf], bfr[nf], acc[mf][nf], 0, 0, 0);
        __syncthreads();   // protect basis rewrite + B buffer reuse
    }

    // --- epilogue: C/D layout col=lane&15, row=(lane>>4)*4+reg
    const int col = lane & 15;
    const int rb = (lane >> 4) * 4;
    float s = 0.f;
    if (mode == 1) s = *scal;
#pragma unroll
    for (int mf = 0; mf < 4; ++mf) {
#pragma unroll
        for (int nf = 0; nf < 4; ++nf) {
            int o = (wv * 4 + nf) * 16 + col;
#pragma unroll
            for (int r = 0; r < 4; ++r) {
                int b = b0 + mf * 16 + rb + r;
                size_t idx = (size_t)b * NHID + o;
                float g = acc[mf][nf][r];
                if (mode == 0) {
                    out[idx] = g;
                } else {
                    float uu = ubuf[idx], vv = vbuf[idx], id = idb[idx];
                    float m = vv + g * (uu - vv);
                    out[idx] = s * m + (1.0f - s) * id;
                }
            }
        }
    }
}

// ---------------------------------------------------------------- final layer (N_OUT=1)
__global__ __launch_bounds__(256) void kan_final(
    const float* __restrict__ h, const float* __restrict__ Cf, float* __restrict__ out)
{
    __shared__ float cf[NHID * 9];   // stride 9 pads bank conflicts
    const int tid = threadIdx.x;
    for (int i = tid; i < KTOT; i += 256)
        cf[(i >> 3) * 9 + (i & 7)] = Cf[i];
    __syncthreads();
    const int wv = tid >> 6, lane = tid & 63;
    const int b0 = blockIdx.x * 64;
#pragma unroll 1
    for (int p = 0; p < 16; ++p) {
        int row = b0 + wv * 16 + p;
        const float* hr = h + (size_t)row * NHID;
        float4 hv = ((const float4*)hr)[lane];   // coalesced: wave covers full row
        const float* hvp = (const float*)&hv;
        float a = 0.f;
#pragma unroll
        for (int j = 0; j < 4; ++j) {
            int i = lane * 4 + j;
            float t = fast_tanh(hvp[j]);
            const float* c = &cf[i * 9];
            float accv = c[0] + c[1] * t;
            float t2 = t + t;
            float Tm = 1.0f, Tc = t;
#pragma unroll
            for (int d = 2; d < 8; ++d) {
                float Tn = fmaf(t2, Tc, -Tm);
                accv = fmaf(c[d], Tn, accv);
                Tm = Tc; Tc = Tn;
            }
            a += accv;
        }
#pragma unroll
        for (int off = 32; off > 0; off >>= 1) a += __shfl_down(a, off);
        if (lane == 0) out[row] = a;
    }
}

// ---------------------------------------------------------------- launch
extern "C" void kernel_launch(void* const* d_in, const int* in_sizes, int n_in,
                              void* d_out, int out_size, void* d_ws, size_t ws_size,
                              hipStream_t stream)
{
    const float* x      = (const float*)d_in[0];
    const float* Brff   = (const float*)d_in[1];
    const float* CU     = (const float*)d_in[2];
    const float* CV     = (const float*)d_in[3];
    const float* Cin    = (const float*)d_in[4];
    const float* Cout   = (const float*)d_in[5];
    const float* alphas = (const float*)d_in[6];
    const float* betas  = (const float*)d_in[7];
    const float* Cf     = (const float*)d_in[8];
    float* out = (float*)d_out;

    char* ws = (char*)d_ws;
    const size_t PW_BYTES  = (size_t)10 * MAT_ELEMS * sizeof(unsigned short); // 10.5 MB
    const size_t ACT_BYTES = (size_t)BATCH * NHID * sizeof(float);            // 33.5 MB
    unsigned short* pw = (unsigned short*)ws;
    float* h  = (float*)(ws + PW_BYTES);
    float* u  = (float*)(ws + PW_BYTES + ACT_BYTES);
    float* v  = (float*)(ws + PW_BYTES + 2 * ACT_BYTES);
    float* t1 = (float*)(ws + PW_BYTES + 3 * ACT_BYTES);

    kan_rff<<<BATCH * 128 / 256, 256, 0, stream>>>(x, Brff, h);
    kan_prepack<<<dim3(256, 10), 256, 0, stream>>>(CU, CV, Cin, Cout, pw);

    // u and v fused via blockIdx.y
    kan_gemm<<<dim3(BATCH / BM, 2), 256, 0, stream>>>(
        h, pw, pw + MAT_ELEMS, u, v, nullptr, nullptr, nullptr, nullptr, 0);

    for (int i = 0; i < 4; ++i) {
        const unsigned short* pwIn  = pw + (size_t)(2 + i) * MAT_ELEMS;
        const unsigned short* pwOut = pw + (size_t)(6 + i) * MAT_ELEMS;
        // t1 = beta*(v + g*(u-v)) + (1-beta)*h
        kan_gemm<<<dim3(BATCH / BM, 1), 256, 0, stream>>>(
            h, pwIn, nullptr, t1, nullptr, u, v, h, betas + i, 1);
        // h = alpha*(v + g*(u-v)) + (1-alpha)*h   (in-place safe: per-element read->write)
        kan_gemm<<<dim3(BATCH / BM, 1), 256, 0, stream>>>(
            t1, pwOut, nullptr, h, nullptr, u, v, h, alphas + i, 1);
    }

    kan_final<<<BATCH / 64, 256, 0, stream>>>(h, Cf, out);
}

// Round 2
// 723.619 us; speedup vs baseline: 1.2601x; 1.2601x over previous
//
#include <hip/hip_runtime.h>
#include <cstdint>
#include <cstddef>

#define BATCH 32768
#define NHID 256
#define KTOT 2048            // NHID * 8
#define BM 64                // batch rows per block
#define BK 32                // K per MFMA chunk
#define NCHUNK (KTOT / BK)   // 64
#define MAT_ELEMS (NHID * KTOT)    // 524288 elements per weight matrix
#define CHUNK_SHORTS (16 * 64 * 8) // 8192 shorts = 16KB per K-chunk of packed W
#define BST 40               // basis row stride in shorts (80B: 16B-aligned, worked R1)

typedef __attribute__((ext_vector_type(8))) short short8;
typedef __attribute__((ext_vector_type(4))) float f32x4;
typedef __attribute__((ext_vector_type(4))) int int4v;

__device__ __forceinline__ float fast_tanh(float x) {
    // t = 1 - 2/(e^{2x}+1); monotone, |t|<1, no NaN/Inf for any finite x
    float e = __expf(2.0f * x);
    return 1.0f - 2.0f / (e + 1.0f);
}

__device__ __forceinline__ unsigned short f2bf(float f) {
    union { float f; unsigned u; } v; v.f = f;
    unsigned r = v.u + 0x7fffu + ((v.u >> 16) & 1u);  // RNE (prepack only)
    return (unsigned short)(r >> 16);
}

// lgkm-only barrier (CK idiom): basis LDS handoff without draining vmcnt —
// global B-fragment prefetches stay in flight across the barrier.
__device__ __forceinline__ void block_sync_lds() {
    asm volatile("s_waitcnt lgkmcnt(0)" ::: "memory");
    __builtin_amdgcn_s_barrier();
    asm volatile("" ::: "memory");
}

// T0..T7 of tanh(hv), packed to 8 bf16 in an int4: round-half-up + v_perm pack
__device__ __forceinline__ int4v cheb_pack(float hv) {
    float t = fast_tanh(hv);
    float t2 = t + t;
    unsigned u[8];
    union { float f; unsigned q; } c;
    c.f = 1.0f; u[0] = c.q;
    c.f = t;    u[1] = c.q;
    float Tm = 1.0f, Tc = t;
#pragma unroll
    for (int d = 2; d < 8; ++d) {
        float Tn = fmaf(t2, Tc, -Tm);   // T_d = 2t*T_{d-1} - T_{d-2}
        c.f = Tn; u[d] = c.q;
        Tm = Tc; Tc = Tn;
    }
#pragma unroll
    for (int i = 0; i < 8; ++i) u[i] += 0x8000u;   // round-half-up to bf16
    int4v p;
    p.x = (int)__builtin_amdgcn_perm(u[1], u[0], 0x07060302);
    p.y = (int)__builtin_amdgcn_perm(u[3], u[2], 0x07060302);
    p.z = (int)__builtin_amdgcn_perm(u[5], u[4], 0x07060302);
    p.w = (int)__builtin_amdgcn_perm(u[7], u[6], 0x07060302);
    return p;
}

// ---------------------------------------------------------------- RFF embed
__global__ __launch_bounds__(256) void kan_rff(
    const float* __restrict__ x, const float* __restrict__ B, float* __restrict__ h)
{
    int t = blockIdx.x * 256 + threadIdx.x;   // over BATCH*128
    int j = t & 127;
    int b = t >> 7;
    float x0 = x[b * 3 + 0], x1 = x[b * 3 + 1], x2 = x[b * 3 + 2];
    float z = x0 * B[j] + x1 * B[128 + j] + x2 * B[256 + j];
    float sn, cs;
    __sincosf(z, &sn, &cs);
    h[(size_t)b * NHID + j] = cs;
    h[(size_t)b * NHID + 128 + j] = sn;
}

// ------------------------------------------------- weight prepack to bf16 frag order
// packed[((kc*16 + nt)*64 + lane)*8 + j] = bf16( W[nt*16 + (lane&15)][kc*32 + (lane>>4)*8 + j] )
__global__ __launch_bounds__(256) void kan_prepack(
    const float* __restrict__ CU, const float* __restrict__ CV,
    const float* __restrict__ Cin, const float* __restrict__ Cout,
    unsigned short* __restrict__ pw)
{
    int mat = blockIdx.y;   // 0=CU 1=CV 2..5=Cin[i] 6..9=Cout[i]
    const float* src;
    if (mat == 0) src = CU;
    else if (mat == 1) src = CV;
    else if (mat < 6) src = Cin + (size_t)(mat - 2) * MAT_ELEMS;
    else src = Cout + (size_t)(mat - 6) * MAT_ELEMS;
    unsigned short* dst = pw + (size_t)mat * MAT_ELEMS;

    int p8 = blockIdx.x * 256 + threadIdx.x;   // 0..65535 (16B groups)
    int l  = p8 & 63;
    int nt = (p8 >> 6) & 15;
    int kc = p8 >> 10;
    int o = nt * 16 + (l & 15);
    int k = kc * 32 + ((l >> 4) << 3);
    const float* s = src + (size_t)o * KTOT + k;
    short8 v;
#pragma unroll
    for (int j = 0; j < 8; ++j) v[j] = (short)f2bf(s[j]);
    *(short8*)(dst + (size_t)p8 * 8) = v;
}

// ---------------------------------------------------------------- fused KAN GEMM
// Y[b,o] = sum_k T_d(tanh(act[b,i])) * W[o,k],  k = i*8+d
// mode 0: out = g                      (u/v heads; blockIdx.y selects pw/out)
// mode 1: out = s*(v + g*(u-v)) + (1-s)*idb    (s = *scal; residual blend)
//
// Structure: B-fragments load global->VGPR directly (prepacked lane order,
// double-buffered in registers); only the Chebyshev basis goes through LDS
// (double-buffered, ONE lgkm-only barrier per chunk). No vmcnt drain anywhere
// in the K-loop.
__global__ __launch_bounds__(256) void kan_gemm(
    const float* __restrict__ act,
    const unsigned short* __restrict__ pw0,
    const unsigned short* __restrict__ pw1,
    float* out0, float* out1,
    const float* __restrict__ ubuf, const float* __restrict__ vbuf,
    const float* idb, const float* __restrict__ scal,
    int mode)
{
    __shared__ unsigned short basis[2][BM * BST];   // 2 x 5120B

    const int tid = threadIdx.x;
    const int wv = tid >> 6;
    const int lane = tid & 63;
    const int b0 = blockIdx.x * BM;

    const unsigned short* pw = (blockIdx.y == 0) ? pw0 : pw1;
    float* out = (blockIdx.y == 0) ? out0 : out1;

    f32x4 acc[4][4];
#pragma unroll
    for (int i = 0; i < 4; ++i)
#pragma unroll
        for (int j = 0; j < 4; ++j)
            acc[i][j] = (f32x4){0.f, 0.f, 0.f, 0.f};

    // basis-producer role: row br (0..63), input-within-chunk bil (0..3)
    const int br = tid >> 2;
    const int bil = tid & 3;
    const float* hrow = act + (size_t)(b0 + br) * NHID;
    unsigned short* bw0 = &basis[0][br * BST + bil * 8];
    unsigned short* bw1 = &basis[1][br * BST + bil * 8];

    // A-frag read base (per MFMA layout: row = mf*16 + (lane&15), quad = lane>>4)
    const unsigned short* ar0 = &basis[0][(lane & 15) * BST + (lane >> 4) * 8];
    const unsigned short* ar1 = &basis[1][(lane & 15) * BST + (lane >> 4) * 8];

    // per-lane global B-fragment pointers (chunk 0); chunk kc at +kc*CHUNK_SHORTS
    const unsigned short* pB[4];
#pragma unroll
    for (int nf = 0; nf < 4; ++nf)
        pB[nf] = pw + ((size_t)(wv * 4 + nf) * 64 + lane) * 8;

    short8 bcur[4], bnxt[4];
#pragma unroll
    for (int nf = 0; nf < 4; ++nf) bcur[nf] = *(const short8*)pB[nf];

    float hnext = hrow[bil];
    *(int4v*)bw0 = cheb_pack(hnext);
    hnext = hrow[4 + bil];
    block_sync_lds();

#pragma unroll 1
    for (int kc = 0; kc < NCHUNK; kc += 2) {
        // ---- even step: consume basis[0] + bcur; prefetch chunk kc+1 -> basis[1], bnxt
        {
#pragma unroll
            for (int nf = 0; nf < 4; ++nf)
                bnxt[nf] = *(const short8*)(pB[nf] + (size_t)(kc + 1) * CHUNK_SHORTS);
            *(int4v*)bw1 = cheb_pack(hnext);
            hnext = hrow[((kc + 2) & (NCHUNK - 1)) * 4 + bil];   // wraps harmlessly at end

            short8 af[4];
#pragma unroll
            for (int mf = 0; mf < 4; ++mf)
                af[mf] = *(const short8*)(ar0 + mf * 16 * BST);
#pragma unroll
            for (int mf = 0; mf < 4; ++mf)
#pragma unroll
                for (int nf = 0; nf < 4; ++nf)
                    acc[mf][nf] = __builtin_amdgcn_mfma_f32_16x16x32_bf16(
                        af[mf], bcur[nf], acc[mf][nf], 0, 0, 0);
            block_sync_lds();
        }
        // ---- odd step: consume basis[1] + bnxt; prefetch chunk kc+2 -> basis[0], bcur
        {
            if (kc + 2 < NCHUNK) {
#pragma unroll
                for (int nf = 0; nf < 4; ++nf)
                    bcur[nf] = *(const short8*)(pB[nf] + (size_t)(kc + 2) * CHUNK_SHORTS);
                *(int4v*)bw0 = cheb_pack(hnext);
                hnext = hrow[((kc + 3) & (NCHUNK - 1)) * 4 + bil];
            }
            short8 af[4];
#pragma unroll
            for (int mf = 0; mf < 4; ++mf)
                af[mf] = *(const short8*)(ar1 + mf * 16 * BST);
#pragma unroll
            for (int mf = 0; mf < 4; ++mf)
#pragma unroll
                for (int nf = 0; nf < 4; ++nf)
                    acc[mf][nf] = __builtin_amdgcn_mfma_f32_16x16x32_bf16(
                        af[mf], bnxt[nf], acc[mf][nf], 0, 0, 0);
            block_sync_lds();
        }
    }

    // --- epilogue: C/D layout col=lane&15, row=(lane>>4)*4+reg
    const int col = lane & 15;
    const int rb = (lane >> 4) * 4;
    float s = 0.f;
    if (mode == 1) s = *scal;
#pragma unroll
    for (int mf = 0; mf < 4; ++mf) {
#pragma unroll
        for (int nf = 0; nf < 4; ++nf) {
            int o = (wv * 4 + nf) * 16 + col;
#pragma unroll
            for (int r = 0; r < 4; ++r) {
                int b = b0 + mf * 16 + rb + r;
                size_t idx = (size_t)b * NHID + o;
                float g = acc[mf][nf][r];
                if (mode == 0) {
                    out[idx] = g;
                } else {
                    float uu = ubuf[idx], vv = vbuf[idx], id = idb[idx];
                    float m = vv + g * (uu - vv);
                    out[idx] = s * m + (1.0f - s) * id;
                }
            }
        }
    }
}

// ---------------------------------------------------------------- final layer (N_OUT=1)
__global__ __launch_bounds__(256) void kan_final(
    const float* __restrict__ h, const float* __restrict__ Cf, float* __restrict__ out)
{
    __shared__ float cf[NHID * 9];   // stride 9 pads bank conflicts
    const int tid = threadIdx.x;
    for (int i = tid; i < KTOT; i += 256)
        cf[(i >> 3) * 9 + (i & 7)] = Cf[i];
    __syncthreads();
    const int wv = tid >> 6, lane = tid & 63;
    const int b0 = blockIdx.x * 64;
#pragma unroll 1
    for (int p = 0; p < 16; ++p) {
        int row = b0 + wv * 16 + p;
        const float* hr = h + (size_t)row * NHID;
        float4 hv = ((const float4*)hr)[lane];   // coalesced: wave covers full row
        const float* hvp = (const float*)&hv;
        float a = 0.f;
#pragma unroll
        for (int j = 0; j < 4; ++j) {
            int i = lane * 4 + j;
            float t = fast_tanh(hvp[j]);
            const float* c = &cf[i * 9];
            float accv = c[0] + c[1] * t;
            float t2 = t + t;
            float Tm = 1.0f, Tc = t;
#pragma unroll
            for (int d = 2; d < 8; ++d) {
                float Tn = fmaf(t2, Tc, -Tm);
                accv = fmaf(c[d], Tn, accv);
                Tm = Tc; Tc = Tn;
            }
            a += accv;
        }
#pragma unroll
        for (int off = 32; off > 0; off >>= 1) a += __shfl_down(a, off);
        if (lane == 0) out[row] = a;
    }
}

// ---------------------------------------------------------------- launch
extern "C" void kernel_launch(void* const* d_in, const int* in_sizes, int n_in,
                              void* d_out, int out_size, void* d_ws, size_t ws_size,
                              hipStream_t stream)
{
    const float* x      = (const float*)d_in[0];
    const float* Brff   = (const float*)d_in[1];
    const float* CU     = (const float*)d_in[2];
    const float* CV     = (const float*)d_in[3];
    const float* Cin    = (const float*)d_in[4];
    const float* Cout   = (const float*)d_in[5];
    const float* alphas = (const float*)d_in[6];
    const float* betas  = (const float*)d_in[7];
    const float* Cf     = (const float*)d_in[8];
    float* out = (float*)d_out;

    char* ws = (char*)d_ws;
    const size_t PW_BYTES  = (size_t)10 * MAT_ELEMS * sizeof(unsigned short); // 10.5 MB
    const size_t ACT_BYTES = (size_t)BATCH * NHID * sizeof(float);            // 33.5 MB
    unsigned short* pw = (unsigned short*)ws;
    float* h  = (float*)(ws + PW_BYTES);
    float* u  = (float*)(ws + PW_BYTES + ACT_BYTES);
    float* v  = (float*)(ws + PW_BYTES + 2 * ACT_BYTES);
    float* t1 = (float*)(ws + PW_BYTES + 3 * ACT_BYTES);

    kan_rff<<<BATCH * 128 / 256, 256, 0, stream>>>(x, Brff, h);
    kan_prepack<<<dim3(256, 10), 256, 0, stream>>>(CU, CV, Cin, Cout, pw);

    // u and v fused via blockIdx.y
    kan_gemm<<<dim3(BATCH / BM, 2), 256, 0, stream>>>(
        h, pw, pw + MAT_ELEMS, u, v, nullptr, nullptr, nullptr, nullptr, 0);

    for (int i = 0; i < 4; ++i) {
        const unsigned short* pwIn  = pw + (size_t)(2 + i) * MAT_ELEMS;
        const unsigned short* pwOut = pw + (size_t)(6 + i) * MAT_ELEMS;
        // t1 = beta*(v + g*(u-v)) + (1-beta)*h
        kan_gemm<<<dim3(BATCH / BM, 1), 256, 0, stream>>>(
            h, pwIn, nullptr, t1, nullptr, u, v, h, betas + i, 1);
        // h = alpha*(v + g*(u-v)) + (1-alpha)*h   (in-place safe: per-element read->write)
        kan_gemm<<<dim3(BATCH / BM, 1), 256, 0, stream>>>(
            t1, pwOut, nullptr, h, nullptr, u, v, h, alphas + i, 1);
    }

    kan_final<<<BATCH / 64, 256, 0, stream>>>(h, Cf, out);
}

// Round 3
// 677.199 us; speedup vs baseline: 1.3465x; 1.0685x over previous
//
#include <hip/hip_runtime.h>
#include <cstdint>
#include <cstddef>

#define BATCH 32768
#define NHID 256
#define KTOT 2048            // NHID * 8
#define BM 64                // batch rows per block
#define BK 32                // K per MFMA chunk
#define NCHUNK (KTOT / BK)   // 64
#define MAT_ELEMS (NHID * KTOT)    // 524288 elements per weight matrix
#define PAIR_SHORTS (16 * 64 * 16) // 16384 shorts = 32KB per chunk-PAIR of packed W
#define BST 40               // basis row stride in shorts (80B, 16B-aligned)
#define BUF_SHORTS (BM * BST)      // 2560 shorts per basis buffer

typedef __attribute__((ext_vector_type(8))) short short8;
typedef __attribute__((ext_vector_type(4))) float f32x4;
typedef __attribute__((ext_vector_type(4))) int int4v;

__device__ __forceinline__ float fast_tanh(float x) {
    float e = __expf(2.0f * x);
    return 1.0f - 2.0f / (e + 1.0f);
}

__device__ __forceinline__ unsigned short f2bf(float f) {
    union { float f; unsigned u; } v; v.f = f;
    unsigned r = v.u + 0x7fffu + ((v.u >> 16) & 1u);  // RNE (prepack only)
    return (unsigned short)(r >> 16);
}

// lgkm-only barrier (CK idiom): LDS handoff without draining vmcnt —
// in-flight global B-fragment prefetches survive the barrier.
__device__ __forceinline__ void block_sync_lds() {
    asm volatile("s_waitcnt lgkmcnt(0)" ::: "memory");
    __builtin_amdgcn_s_barrier();
    asm volatile("" ::: "memory");
}

// T0..T7 of tanh(hv), packed to 8 bf16 in an int4: round-half-up + v_perm pack
__device__ __forceinline__ int4v cheb_pack(float hv) {
    float t = fast_tanh(hv);
    float t2 = t + t;
    unsigned u[8];
    union { float f; unsigned q; } c;
    c.f = 1.0f; u[0] = c.q;
    c.f = t;    u[1] = c.q;
    float Tm = 1.0f, Tc = t;
#pragma unroll
    for (int d = 2; d < 8; ++d) {
        float Tn = fmaf(t2, Tc, -Tm);   // T_d = 2t*T_{d-1} - T_{d-2}
        c.f = Tn; u[d] = c.q;
        Tm = Tc; Tc = Tn;
    }
#pragma unroll
    for (int i = 0; i < 8; ++i) u[i] += 0x8000u;   // round-half-up to bf16
    int4v p;
    p.x = (int)__builtin_amdgcn_perm(u[1], u[0], 0x07060302);
    p.y = (int)__builtin_amdgcn_perm(u[3], u[2], 0x07060302);
    p.z = (int)__builtin_amdgcn_perm(u[5], u[4], 0x07060302);
    p.w = (int)__builtin_amdgcn_perm(u[7], u[6], 0x07060302);
    return p;
}

// ---------------------------------------------------------------- RFF embed
__global__ __launch_bounds__(256) void kan_rff(
    const float* __restrict__ x, const float* __restrict__ B, float* __restrict__ h)
{
    int t = blockIdx.x * 256 + threadIdx.x;   // over BATCH*128
    int j = t & 127;
    int b = t >> 7;
    float x0 = x[b * 3 + 0], x1 = x[b * 3 + 1], x2 = x[b * 3 + 2];
    float z = x0 * B[j] + x1 * B[128 + j] + x2 * B[256 + j];
    float sn, cs;
    __sincosf(z, &sn, &cs);
    h[(size_t)b * NHID + j] = cs;
    h[(size_t)b * NHID + 128 + j] = sn;
}

// ------------------------------------------------- weight prepack, chunk-paired frag order
// pw[(((ks*16 + nt)*64 + lane)*2 + par)*8 + j]
//   = bf16( W[nt*16 + (lane&15)][(ks*2+par)*32 + (lane>>4)*8 + j] )
__global__ __launch_bounds__(256) void kan_prepack(
    const float* __restrict__ CU, const float* __restrict__ CV,
    const float* __restrict__ Cin, const float* __restrict__ Cout,
    unsigned short* __restrict__ pw)
{
    int mat = blockIdx.y;   // 0=CU 1=CV 2..5=Cin[i] 6..9=Cout[i]
    const float* src;
    if (mat == 0) src = CU;
    else if (mat == 1) src = CV;
    else if (mat < 6) src = Cin + (size_t)(mat - 2) * MAT_ELEMS;
    else src = Cout + (size_t)(mat - 6) * MAT_ELEMS;
    unsigned short* dst = pw + (size_t)mat * MAT_ELEMS;

    int p8 = blockIdx.x * 256 + threadIdx.x;   // 0..65535 (16B groups)
    int par = p8 & 1;
    int l   = (p8 >> 1) & 63;
    int nt  = (p8 >> 7) & 15;
    int ks  = p8 >> 11;
    int o = nt * 16 + (l & 15);
    int k = ks * 64 + par * 32 + ((l >> 4) << 3);
    const float* s = src + (size_t)o * KTOT + k;
    short8 v;
#pragma unroll
    for (int j = 0; j < 8; ++j) v[j] = (short)f2bf(s[j]);
    *(short8*)(dst + (size_t)p8 * 8) = v;
}

// ---------------------------------------------------------------- fused KAN GEMM
// 512 threads = 8 waves; wave: m 0..63 (4 mf), n = wv*32 (2 nf). 16 waves/CU.
// 4 basis buffers, 1 lgkm-only barrier per 2 chunks; B frags global->VGPR,
// chunk-paired layout (one pointer increment per superstep).
__global__ __launch_bounds__(512, 4) void kan_gemm(
    const float* __restrict__ act,
    const unsigned short* __restrict__ pw0,
    const unsigned short* __restrict__ pw1,
    float* out0, float* out1,
    const float* __restrict__ ubuf, const float* __restrict__ vbuf,
    const float* idb, const float* __restrict__ scal,
    int mode)
{
    __shared__ __attribute__((aligned(16))) unsigned short basis[4][BUF_SHORTS]; // 20KB

    const int tid = threadIdx.x;
    const int wv = tid >> 6;
    const int lane = tid & 63;
    const int b0 = blockIdx.x * BM;

    const unsigned short* pw = (blockIdx.y == 0) ? pw0 : pw1;
    float* out = (blockIdx.y == 0) ? out0 : out1;

    f32x4 acc[4][2];
#pragma unroll
    for (int i = 0; i < 4; ++i)
#pragma unroll
        for (int j = 0; j < 2; ++j)
            acc[i][j] = (f32x4){0.f, 0.f, 0.f, 0.f};

    // producer role: 256 slots x 2 parities. waves 0-3 -> even chunks, 4-7 -> odd.
    const int pr = tid & 255;
    const int p = tid >> 8;          // chunk parity this thread produces
    const int br = pr >> 2;          // basis row 0..63
    const int bil = pr & 3;          // input-within-chunk 0..3
    const float* hrow = act + (size_t)(b0 + br) * NHID;
    unsigned short* bwbase = &basis[0][br * BST + bil * 8];
    const unsigned short* arbase = &basis[0][(lane & 15) * BST + (lane >> 4) * 8];

    // B fragment pointers (chunk-pair 0), per lane, nf = 0,1
    const unsigned short* pB0 = pw + ((size_t)((wv * 2 + 0) * 64 + lane) * 16);
    const unsigned short* pB1 = pw + ((size_t)((wv * 2 + 1) * 64 + lane) * 16);

    short8 bf[2][2];   // [par][nf]
    bf[0][0] = *(const short8*)pB0;
    bf[0][1] = *(const short8*)pB1;
    bf[1][0] = *(const short8*)(pB0 + 8);
    bf[1][1] = *(const short8*)(pB1 + 8);
    pB0 += PAIR_SHORTS;
    pB1 += PAIR_SHORTS;

    // produce superstep-0 basis (chunks 0,1 -> bufs 0,1)
    float hv = hrow[p * 4 + bil];
    *(int4v*)(bwbase + p * BUF_SHORTS) = cheb_pack(hv);
    float hn = hrow[(2 + p) * 4 + bil];   // for superstep-1 production
    block_sync_lds();

#pragma unroll 1
    for (int s2 = 0; s2 < 16; ++s2) {
#pragma unroll
        for (int half = 0; half < 2; ++half) {
            const int CUR = half * 2;        // consumer buf pair: 0,1 or 2,3
            const int NXT = 2 - half * 2;    // producer buf pair: 2,3 or 0,1
            short8 af;
            // chunk even (par 0)
#pragma unroll
            for (int mf = 0; mf < 4; ++mf) {
                af = *(const short8*)(arbase + CUR * BUF_SHORTS + mf * 16 * BST);
                acc[mf][0] = __builtin_amdgcn_mfma_f32_16x16x32_bf16(af, bf[0][0], acc[mf][0], 0, 0, 0);
                acc[mf][1] = __builtin_amdgcn_mfma_f32_16x16x32_bf16(af, bf[0][1], acc[mf][1], 0, 0, 0);
            }
            // prefetch next superstep, par 0 (reads past last matrix land in ws activations: harmless)
            bf[0][0] = *(const short8*)pB0;
            bf[0][1] = *(const short8*)pB1;
            // chunk odd (par 1)
#pragma unroll
            for (int mf = 0; mf < 4; ++mf) {
                af = *(const short8*)(arbase + (CUR + 1) * BUF_SHORTS + mf * 16 * BST);
                acc[mf][0] = __builtin_amdgcn_mfma_f32_16x16x32_bf16(af, bf[1][0], acc[mf][0], 0, 0, 0);
                acc[mf][1] = __builtin_amdgcn_mfma_f32_16x16x32_bf16(af, bf[1][1], acc[mf][1], 0, 0, 0);
            }
            bf[1][0] = *(const short8*)(pB0 + 8);
            bf[1][1] = *(const short8*)(pB1 + 8);
            pB0 += PAIR_SHORTS;
            pB1 += PAIR_SHORTS;
            // produce next superstep's basis (one cheb per thread per 2 chunks)
            *(int4v*)(bwbase + (NXT + p) * BUF_SHORTS) = cheb_pack(hn);
            hn = hrow[(((s2 * 2 + half) * 2 + 4 + p) * 4 + bil) & 255];
            block_sync_lds();
        }
    }

    // --- epilogue: C/D layout col=lane&15, row=(lane>>4)*4+reg
    const int col = lane & 15;
    const int rb = (lane >> 4) * 4;
    float s = 0.f;
    if (mode == 1) s = *scal;
#pragma unroll
    for (int mf = 0; mf < 4; ++mf) {
#pragma unroll
        for (int nf = 0; nf < 2; ++nf) {
            int o = (wv * 2 + nf) * 16 + col;
#pragma unroll
            for (int r = 0; r < 4; ++r) {
                int b = b0 + mf * 16 + rb + r;
                size_t idx = (size_t)b * NHID + o;
                float g = acc[mf][nf][r];
                if (mode == 0) {
                    out[idx] = g;
                } else {
                    float uu = ubuf[idx], vv = vbuf[idx], id = idb[idx];
                    float m = vv + g * (uu - vv);
                    out[idx] = s * m + (1.0f - s) * id;
                }
            }
        }
    }
}

// ---------------------------------------------------------------- final layer (N_OUT=1)
__global__ __launch_bounds__(256) void kan_final(
    const float* __restrict__ h, const float* __restrict__ Cf, float* __restrict__ out)
{
    __shared__ float cf[NHID * 9];
    const int tid = threadIdx.x;
    for (int i = tid; i < KTOT; i += 256)
        cf[(i >> 3) * 9 + (i & 7)] = Cf[i];
    __syncthreads();
    const int wv = tid >> 6, lane = tid & 63;
    const int b0 = blockIdx.x * 64;
#pragma unroll 1
    for (int p = 0; p < 16; ++p) {
        int row = b0 + wv * 16 + p;
        const float* hr = h + (size_t)row * NHID;
        float4 hv = ((const float4*)hr)[lane];
        const float* hvp = (const float*)&hv;
        float a = 0.f;
#pragma unroll
        for (int j = 0; j < 4; ++j) {
            int i = lane * 4 + j;
            float t = fast_tanh(hvp[j]);
            const float* c = &cf[i * 9];
            float accv = c[0] + c[1] * t;
            float t2 = t + t;
            float Tm = 1.0f, Tc = t;
#pragma unroll
            for (int d = 2; d < 8; ++d) {
                float Tn = fmaf(t2, Tc, -Tm);
                accv = fmaf(c[d], Tn, accv);
                Tm = Tc; Tc = Tn;
            }
            a += accv;
        }
#pragma unroll
        for (int off = 32; off > 0; off >>= 1) a += __shfl_down(a, off);
        if (lane == 0) out[row] = a;
    }
}

// ---------------------------------------------------------------- launch
extern "C" void kernel_launch(void* const* d_in, const int* in_sizes, int n_in,
                              void* d_out, int out_size, void* d_ws, size_t ws_size,
                              hipStream_t stream)
{
    const float* x      = (const float*)d_in[0];
    const float* Brff   = (const float*)d_in[1];
    const float* CU     = (const float*)d_in[2];
    const float* CV     = (const float*)d_in[3];
    const float* Cin    = (const float*)d_in[4];
    const float* Cout   = (const float*)d_in[5];
    const float* alphas = (const float*)d_in[6];
    const float* betas  = (const float*)d_in[7];
    const float* Cf     = (const float*)d_in[8];
    float* out = (float*)d_out;

    char* ws = (char*)d_ws;
    const size_t PW_BYTES  = (size_t)10 * MAT_ELEMS * sizeof(unsigned short); // 10.5 MB
    const size_t ACT_BYTES = (size_t)BATCH * NHID * sizeof(float);            // 33.5 MB
    unsigned short* pw = (unsigned short*)ws;
    float* h  = (float*)(ws + PW_BYTES);
    float* u  = (float*)(ws + PW_BYTES + ACT_BYTES);
    float* v  = (float*)(ws + PW_BYTES + 2 * ACT_BYTES);
    float* t1 = (float*)(ws + PW_BYTES + 3 * ACT_BYTES);

    kan_rff<<<BATCH * 128 / 256, 256, 0, stream>>>(x, Brff, h);
    kan_prepack<<<dim3(256, 10), 256, 0, stream>>>(CU, CV, Cin, Cout, pw);

    // u and v fused via blockIdx.y
    kan_gemm<<<dim3(BATCH / BM, 2), 512, 0, stream>>>(
        h, pw, pw + MAT_ELEMS, u, v, nullptr, nullptr, nullptr, nullptr, 0);

    for (int i = 0; i < 4; ++i) {
        const unsigned short* pwIn  = pw + (size_t)(2 + i) * MAT_ELEMS;
        const unsigned short* pwOut = pw + (size_t)(6 + i) * MAT_ELEMS;
        kan_gemm<<<dim3(BATCH / BM, 1), 512, 0, stream>>>(
            h, pwIn, nullptr, t1, nullptr, u, v, h, betas + i, 1);
        kan_gemm<<<dim3(BATCH / BM, 1), 512, 0, stream>>>(
            t1, pwOut, nullptr, h, nullptr, u, v, h, alphas + i, 1);
    }

    kan_final<<<BATCH / 64, 256, 0, stream>>>(h, Cf, out);
}

// Round 4
// 670.907 us; speedup vs baseline: 1.3592x; 1.0094x over previous
//
#include <hip/hip_runtime.h>
#include <cstdint>
#include <cstddef>

#define BATCH 32768
#define NHID 256
#define KTOT 2048            // NHID * 8
#define BM 64                // batch rows per block
#define NCHUNK 64            // K chunks of 32
#define MAT_ELEMS (NHID * KTOT)    // 524288 elements per weight matrix
#define PAIR_SHORTS (16 * 64 * 16) // 16384 shorts = 32KB per chunk-PAIR of packed W
#define BUFQ 512             // shorts per (buf,mf) fragment group = 64 lanes * 8
#define BUFS 2048            // shorts per basis buffer = 4 mf * BUFQ

typedef __attribute__((ext_vector_type(8))) short short8;
typedef __attribute__((ext_vector_type(4))) float f32x4;
typedef __attribute__((ext_vector_type(4))) int int4v;

__device__ __forceinline__ float fast_tanh(float x) {
    float e = __expf(2.0f * x);
    return 1.0f - 2.0f / (e + 1.0f);
}

__device__ __forceinline__ unsigned short f2bf(float f) {
    union { float f; unsigned u; } v; v.f = f;
    unsigned r = v.u + 0x7fffu + ((v.u >> 16) & 1u);  // RNE (prepack only)
    return (unsigned short)(r >> 16);
}

// lgkm-only barrier (CK idiom): LDS handoff without draining vmcnt —
// in-flight global B-fragment prefetches survive the barrier.
__device__ __forceinline__ void block_sync_lds() {
    asm volatile("s_waitcnt lgkmcnt(0)" ::: "memory");
    __builtin_amdgcn_s_barrier();
    asm volatile("" ::: "memory");
}

// T0..T7 of tanh(hv), packed to 8 bf16 in an int4: round-half-up + v_perm pack
__device__ __forceinline__ int4v cheb_pack(float hv) {
    float t = fast_tanh(hv);
    float t2 = t + t;
    unsigned u[8];
    union { float f; unsigned q; } c;
    c.f = 1.0f; u[0] = c.q;
    c.f = t;    u[1] = c.q;
    float Tm = 1.0f, Tc = t;
#pragma unroll
    for (int d = 2; d < 8; ++d) {
        float Tn = fmaf(t2, Tc, -Tm);   // T_d = 2t*T_{d-1} - T_{d-2}
        c.f = Tn; u[d] = c.q;
        Tm = Tc; Tc = Tn;
    }
#pragma unroll
    for (int i = 0; i < 8; ++i) u[i] += 0x8000u;   // round-half-up to bf16
    int4v p;
    p.x = (int)__builtin_amdgcn_perm(u[1], u[0], 0x07060302);
    p.y = (int)__builtin_amdgcn_perm(u[3], u[2], 0x07060302);
    p.z = (int)__builtin_amdgcn_perm(u[5], u[4], 0x07060302);
    p.w = (int)__builtin_amdgcn_perm(u[7], u[6], 0x07060302);
    return p;
}

// ---------------------------------------------------------------- RFF embed
__global__ __launch_bounds__(256) void kan_rff(
    const float* __restrict__ x, const float* __restrict__ B, float* __restrict__ h)
{
    int t = blockIdx.x * 256 + threadIdx.x;   // over BATCH*128
    int j = t & 127;
    int b = t >> 7;
    float x0 = x[b * 3 + 0], x1 = x[b * 3 + 1], x2 = x[b * 3 + 2];
    float z = x0 * B[j] + x1 * B[128 + j] + x2 * B[256 + j];
    float sn, cs;
    __sincosf(z, &sn, &cs);
    h[(size_t)b * NHID + j] = cs;
    h[(size_t)b * NHID + 128 + j] = sn;
}

// ------------------------------------------------- weight prepack, chunk-paired frag order
// pw[(((ks*16 + nt)*64 + lane)*2 + par)*8 + j]
//   = bf16( W[nt*16 + (lane&15)][(ks*2+par)*32 + (lane>>4)*8 + j] )
__global__ __launch_bounds__(256) void kan_prepack(
    const float* __restrict__ CU, const float* __restrict__ CV,
    const float* __restrict__ Cin, const float* __restrict__ Cout,
    unsigned short* __restrict__ pw)
{
    int mat = blockIdx.y;   // 0=CU 1=CV 2..5=Cin[i] 6..9=Cout[i]
    const float* src;
    if (mat == 0) src = CU;
    else if (mat == 1) src = CV;
    else if (mat < 6) src = Cin + (size_t)(mat - 2) * MAT_ELEMS;
    else src = Cout + (size_t)(mat - 6) * MAT_ELEMS;
    unsigned short* dst = pw + (size_t)mat * MAT_ELEMS;

    int p8 = blockIdx.x * 256 + threadIdx.x;   // 0..65535 (16B groups)
    int par = p8 & 1;
    int l   = (p8 >> 1) & 63;
    int nt  = (p8 >> 7) & 15;
    int ks  = p8 >> 11;
    int o = nt * 16 + (l & 15);
    int k = ks * 64 + par * 32 + ((l >> 4) << 3);
    const float* s = src + (size_t)o * KTOT + k;
    short8 v;
#pragma unroll
    for (int j = 0; j < 8; ++j) v[j] = (short)f2bf(s[j]);
    *(short8*)(dst + (size_t)p8 * 8) = v;
}

// ---------------------------------------------------------------- fused KAN GEMM
// 512 threads = 8 waves; wave: m 0..63 (4 mf), n = wv*32 (2 nf).
// Basis in MFMA-fragment order [buf][mf][lane][8]: stride-1 conflict-free
// ds_read_b128, immediate-offset addressing. h prefetched distance-4 via
// rotating 4-register buffer (static indices from 8x4 loop split).
__global__ __launch_bounds__(512, 4) void kan_gemm(
    const float* __restrict__ act,
    const unsigned short* __restrict__ pw0,
    const unsigned short* __restrict__ pw1,
    float* out0, float* out1,
    const float* __restrict__ ubuf, const float* __restrict__ vbuf,
    const float* idb, const float* __restrict__ scal,
    int mode)
{
    __shared__ __attribute__((aligned(16))) unsigned short basis[4 * BUFS]; // 16KB

    const int tid = threadIdx.x;
    const int wv = tid >> 6;
    const int lane = tid & 63;
    const int b0 = blockIdx.x * BM;

    const unsigned short* pw = (blockIdx.y == 0) ? pw0 : pw1;
    float* out = (blockIdx.y == 0) ? out0 : out1;

    f32x4 acc[4][2];
#pragma unroll
    for (int i = 0; i < 4; ++i)
#pragma unroll
        for (int j = 0; j < 2; ++j)
            acc[i][j] = (f32x4){0.f, 0.f, 0.f, 0.f};

    // producer role: 256 slots x 2 parities (waves 0-3 even chunks, 4-7 odd)
    const int pr = tid & 255;
    const int p = tid >> 8;          // chunk parity this thread produces
    const int br = pr >> 2;          // basis row 0..63
    const int bil = pr & 3;          // input-within-chunk 0..3
    const float* hrow = act + (size_t)(b0 + br) * NHID;
    const int i0 = 4 * p + bil;      // thread's input index at step t is i0 + 8t
    // writer slot: frag mf=br>>4, lane-slot (bil<<4)|(br&15); +buf*BUFS at use
    unsigned short* bw = &basis[((br >> 4) * 64 + ((bil << 4) | (br & 15))) * 8];
    // reader base: contiguous per lane; +(buf*4+mf)*BUFQ immediates at use
    const unsigned short* ar = &basis[lane * 8];

    // B fragment pointers (chunk-pair 0), per lane, nf = 0,1
    const unsigned short* pB0 = pw + ((size_t)((wv * 2 + 0) * 64 + lane) * 16);
    const unsigned short* pB1 = pw + ((size_t)((wv * 2 + 1) * 64 + lane) * 16);

    short8 bf[2][2];   // [par][nf]
    bf[0][0] = *(const short8*)pB0;
    bf[0][1] = *(const short8*)pB1;
    bf[1][0] = *(const short8*)(pB0 + 8);
    bf[1][1] = *(const short8*)(pB1 + 8);
    pB0 += PAIR_SHORTS;
    pB1 += PAIR_SHORTS;

    // h prefetch window: hbuf[t&3] holds value for production step t
    float hbuf[4];
#pragma unroll
    for (int t = 0; t < 4; ++t) hbuf[t] = hrow[i0 + 8 * t];

    // prologue production: chunk p -> buf p (for half 0), uses t=0
    *(int4v*)(bw + p * BUFS) = cheb_pack(hbuf[0]);
    hbuf[0] = hrow[i0 + 8 * 4];      // slot 0 next used at t=4
    block_sync_lds();

#pragma unroll 1
    for (int o = 0; o < 8; ++o) {
#pragma unroll
        for (int ih = 0; ih < 4; ++ih) {
            const int H = o * 4 + ih;        // half index 0..31; consumes chunks 2H,2H+1
            const int CUR = (ih & 1) * 2;    // consumer buf pair (H&1 == ih&1)
            const int NXT = 2 - CUR;         // producer buf pair
            short8 af;
            // chunk even (par 0): buf CUR
#pragma unroll
            for (int mf = 0; mf < 4; ++mf) {
                af = *(const short8*)(ar + (CUR * 4 + mf) * BUFQ);
                acc[mf][0] = __builtin_amdgcn_mfma_f32_16x16x32_bf16(af, bf[0][0], acc[mf][0], 0, 0, 0);
                acc[mf][1] = __builtin_amdgcn_mfma_f32_16x16x32_bf16(af, bf[0][1], acc[mf][1], 0, 0, 0);
            }
            // prefetch next half's B, par 0 (last-iter overrun reads are harmless)
            bf[0][0] = *(const short8*)pB0;
            bf[0][1] = *(const short8*)pB1;
            // chunk odd (par 1): buf CUR+1
#pragma unroll
            for (int mf = 0; mf < 4; ++mf) {
                af = *(const short8*)(ar + ((CUR + 1) * 4 + mf) * BUFQ);
                acc[mf][0] = __builtin_amdgcn_mfma_f32_16x16x32_bf16(af, bf[1][0], acc[mf][0], 0, 0, 0);
                acc[mf][1] = __builtin_amdgcn_mfma_f32_16x16x32_bf16(af, bf[1][1], acc[mf][1], 0, 0, 0);
            }
            bf[1][0] = *(const short8*)(pB0 + 8);
            bf[1][1] = *(const short8*)(pB1 + 8);
            pB0 += PAIR_SHORTS;
            pB1 += PAIR_SHORTS;
            // produce half H+1's basis (chunk 2H+2+p -> buf NXT+p), value t=H+1
            *(int4v*)(bw + (NXT + p) * BUFS) = cheb_pack(hbuf[(ih + 1) & 3]);
            // refill slot with t=H+5 (wrap &255 keeps address in-row; prefetch-only)
            hbuf[(ih + 1) & 3] = hrow[(i0 + 8 * (H + 5)) & 255];
            block_sync_lds();
        }
    }

    // --- epilogue: C/D layout col=lane&15, row=(lane>>4)*4+reg
    const int col = lane & 15;
    const int rb = (lane >> 4) * 4;
    float s = 0.f;
    if (mode == 1) s = *scal;
#pragma unroll
    for (int mf = 0; mf < 4; ++mf) {
#pragma unroll
        for (int nf = 0; nf < 2; ++nf) {
            int o2 = (wv * 2 + nf) * 16 + col;
#pragma unroll
            for (int r = 0; r < 4; ++r) {
                int b = b0 + mf * 16 + rb + r;
                size_t idx = (size_t)b * NHID + o2;
                float g = acc[mf][nf][r];
                if (mode == 0) {
                    out[idx] = g;
                } else {
                    float uu = ubuf[idx], vv = vbuf[idx], id = idb[idx];
                    float m = vv + g * (uu - vv);
                    out[idx] = s * m + (1.0f - s) * id;
                }
            }
        }
    }
}

// ---------------------------------------------------------------- final layer (N_OUT=1)
__global__ __launch_bounds__(256) void kan_final(
    const float* __restrict__ h, const float* __restrict__ Cf, float* __restrict__ out)
{
    __shared__ float cf[NHID * 9];
    const int tid = threadIdx.x;
    for (int i = tid; i < KTOT; i += 256)
        cf[(i >> 3) * 9 + (i & 7)] = Cf[i];
    __syncthreads();
    const int wv = tid >> 6, lane = tid & 63;
    const int b0 = blockIdx.x * 64;
#pragma unroll 1
    for (int p = 0; p < 16; ++p) {
        int row = b0 + wv * 16 + p;
        const float* hr = h + (size_t)row * NHID;
        float4 hv = ((const float4*)hr)[lane];
        const float* hvp = (const float*)&hv;
        float a = 0.f;
#pragma unroll
        for (int j = 0; j < 4; ++j) {
            int i = lane * 4 + j;
            float t = fast_tanh(hvp[j]);
            const float* c = &cf[i * 9];
            float accv = c[0] + c[1] * t;
            float t2 = t + t;
            float Tm = 1.0f, Tc = t;
#pragma unroll
            for (int d = 2; d < 8; ++d) {
                float Tn = fmaf(t2, Tc, -Tm);
                accv = fmaf(c[d], Tn, accv);
                Tm = Tc; Tc = Tn;
            }
            a += accv;
        }
#pragma unroll
        for (int off = 32; off > 0; off >>= 1) a += __shfl_down(a, off);
        if (lane == 0) out[row] = a;
    }
}

// ---------------------------------------------------------------- launch
extern "C" void kernel_launch(void* const* d_in, const int* in_sizes, int n_in,
                              void* d_out, int out_size, void* d_ws, size_t ws_size,
                              hipStream_t stream)
{
    const float* x      = (const float*)d_in[0];
    const float* Brff   = (const float*)d_in[1];
    const float* CU     = (const float*)d_in[2];
    const float* CV     = (const float*)d_in[3];
    const float* Cin    = (const float*)d_in[4];
    const float* Cout   = (const float*)d_in[5];
    const float* alphas = (const float*)d_in[6];
    const float* betas  = (const float*)d_in[7];
    const float* Cf     = (const float*)d_in[8];
    float* out = (float*)d_out;

    char* ws = (char*)d_ws;
    const size_t PW_BYTES  = (size_t)10 * MAT_ELEMS * sizeof(unsigned short); // 10.5 MB
    const size_t ACT_BYTES = (size_t)BATCH * NHID * sizeof(float);            // 33.5 MB
    unsigned short* pw = (unsigned short*)ws;
    float* h  = (float*)(ws + PW_BYTES);
    float* u  = (float*)(ws + PW_BYTES + ACT_BYTES);
    float* v  = (float*)(ws + PW_BYTES + 2 * ACT_BYTES);
    float* t1 = (float*)(ws + PW_BYTES + 3 * ACT_BYTES);

    kan_rff<<<BATCH * 128 / 256, 256, 0, stream>>>(x, Brff, h);
    kan_prepack<<<dim3(256, 10), 256, 0, stream>>>(CU, CV, Cin, Cout, pw);

    // u and v fused via blockIdx.y
    kan_gemm<<<dim3(BATCH / BM, 2), 512, 0, stream>>>(
        h, pw, pw + MAT_ELEMS, u, v, nullptr, nullptr, nullptr, nullptr, 0);

    for (int i = 0; i < 4; ++i) {
        const unsigned short* pwIn  = pw + (size_t)(2 + i) * MAT_ELEMS;
        const unsigned short* pwOut = pw + (size_t)(6 + i) * MAT_ELEMS;
        kan_gemm<<<dim3(BATCH / BM, 1), 512, 0, stream>>>(
            h, pwIn, nullptr, t1, nullptr, u, v, h, betas + i, 1);
        kan_gemm<<<dim3(BATCH / BM, 1), 512, 0, stream>>>(
            t1, pwOut, nullptr, h, nullptr, u, v, h, alphas + i, 1);
    }

    kan_final<<<BATCH / 64, 256, 0, stream>>>(h, Cf, out);
}